// Round 2
// baseline (557.859 us; speedup 1.0000x reference)
//
#include <hip/hip_runtime.h>
#include <math.h>

#define CIN 256
#define HH 96
#define WW 96
#define HW 9216        // 96*96
#define HS 192
#define WSZ 192
#define HSWS 36864     // 192*192

// ---------------------------------------------------------------------------
// K1: dual 1x1-conv GEMM at low res.
// y[b][m][p] = sum_c W[m][c] * x[b][c][p],  m in [0,512): 0-255 w_base, 256-511 w_process
// Tile: BM=128 (m), BN=128 (p), BK=16. 256 threads, 8x8 micro-tile (split 4+4).
// ---------------------------------------------------------------------------
__global__ __launch_bounds__(256) void gemm_k1(
    const float* __restrict__ x, const float* __restrict__ w_base,
    const float* __restrict__ w_process, float* __restrict__ y)
{
    const int t  = threadIdx.x;
    const int tx = t & 15, ty = t >> 4;
    const int p0 = blockIdx.x * 128;
    const int m0 = blockIdx.y * 128;
    const int b  = blockIdx.z;

    const float* Wp = (m0 < 256) ? (w_base + (size_t)m0 * CIN)
                                 : (w_process + (size_t)(m0 - 256) * CIN);
    const float* Xp = x + (size_t)b * CIN * HW + p0;

    __shared__ __align__(16) float As[16 * 132];  // [k][m], padded stride 132 (16B-aligned rows)
    __shared__ __align__(16) float Bs[16 * 132];  // [k][p]

    float acc[8][8];
#pragma unroll
    for (int i = 0; i < 8; ++i)
#pragma unroll
        for (int j = 0; j < 8; ++j) acc[i][j] = 0.f;

    const int am = t >> 2;          // 0..63  (W row within tile; +64 for second)
    const int ak = (t & 3) << 2;    // 0,4,8,12
    const int bk = t >> 5;          // 0..7
    const int bp = (t & 31) << 2;   // 0..124

    for (int kt = 0; kt < CIN; kt += 16) {
        float4 a0 = *(const float4*)&Wp[(size_t)am * CIN + kt + ak];
        float4 a1 = *(const float4*)&Wp[(size_t)(am + 64) * CIN + kt + ak];
        float4 b0 = *(const float4*)&Xp[(size_t)(kt + bk) * HW + bp];
        float4 b1 = *(const float4*)&Xp[(size_t)(kt + bk + 8) * HW + bp];
        __syncthreads();
        // transpose-store W tile: As[k][m]
        As[(ak + 0) * 132 + am] = a0.x;
        As[(ak + 1) * 132 + am] = a0.y;
        As[(ak + 2) * 132 + am] = a0.z;
        As[(ak + 3) * 132 + am] = a0.w;
        As[(ak + 0) * 132 + am + 64] = a1.x;
        As[(ak + 1) * 132 + am + 64] = a1.y;
        As[(ak + 2) * 132 + am + 64] = a1.z;
        As[(ak + 3) * 132 + am + 64] = a1.w;
        *(float4*)&Bs[bk * 132 + bp] = b0;
        *(float4*)&Bs[(bk + 8) * 132 + bp] = b1;
        __syncthreads();
#pragma unroll
        for (int kk = 0; kk < 16; ++kk) {
            float4 av0 = *(const float4*)&As[kk * 132 + (ty << 2)];
            float4 av1 = *(const float4*)&As[kk * 132 + 64 + (ty << 2)];
            float4 bv0 = *(const float4*)&Bs[kk * 132 + (tx << 2)];
            float4 bv1 = *(const float4*)&Bs[kk * 132 + 64 + (tx << 2)];
            float a8[8] = {av0.x, av0.y, av0.z, av0.w, av1.x, av1.y, av1.z, av1.w};
            float b8[8] = {bv0.x, bv0.y, bv0.z, bv0.w, bv1.x, bv1.y, bv1.z, bv1.w};
#pragma unroll
            for (int i = 0; i < 8; ++i)
#pragma unroll
                for (int j = 0; j < 8; ++j)
                    acc[i][j] = fmaf(a8[i], b8[j], acc[i][j]);
        }
    }

    float* Yp = y + ((size_t)b * 512 + m0) * HW + p0;
#pragma unroll
    for (int mi = 0; mi < 8; ++mi) {
        int row = (mi < 4) ? ((ty << 2) + mi) : (64 + (ty << 2) + (mi - 4));
        float4 v0 = {acc[mi][0], acc[mi][1], acc[mi][2], acc[mi][3]};
        float4 v1 = {acc[mi][4], acc[mi][5], acc[mi][6], acc[mi][7]};
        *(float4*)&Yp[(size_t)row * HW + (tx << 2)] = v0;
        *(float4*)&Yp[(size_t)row * HW + 64 + (tx << 2)] = v1;
    }
}

// ---------------------------------------------------------------------------
// K1b: transposed-conv (k=s=2) + tanh/sigmoid -> per-high-res-pixel (dx,dy).
// coord[b][o][2i+k][2j+l] = sum_c x[b][c][i][j] * w_tc[c][o][k][l]
// dx = lam*tanh(coord[0])*sigmoid(coord[2]); dy = lam*tanh(coord[1])*sigmoid(coord[3])
// ---------------------------------------------------------------------------
__global__ __launch_bounds__(256) void tconv_k1b(
    const float* __restrict__ x, const float* __restrict__ w_tc,
    float2* __restrict__ dxdy)
{
    __shared__ __align__(16) float wl[CIN * 16];
    const int t = threadIdx.x;
#pragma unroll
    for (int i = 0; i < 16; ++i) wl[t + i * 256] = w_tc[t + i * 256];
    __syncthreads();

    const int pg = blockIdx.x * 256 + t;   // 0..36863 (B*HW)
    const int b = pg / HW, p = pg % HW;
    const float* xp = x + (size_t)b * CIN * HW + p;

    float acc[16];
#pragma unroll
    for (int r = 0; r < 16; ++r) acc[r] = 0.f;

    for (int c = 0; c < CIN; ++c) {
        float xv = xp[(size_t)c * HW];
#pragma unroll
        for (int r4 = 0; r4 < 4; ++r4) {
            float4 wv = *(const float4*)&wl[c * 16 + r4 * 4];
            acc[r4 * 4 + 0] = fmaf(xv, wv.x, acc[r4 * 4 + 0]);
            acc[r4 * 4 + 1] = fmaf(xv, wv.y, acc[r4 * 4 + 1]);
            acc[r4 * 4 + 2] = fmaf(xv, wv.z, acc[r4 * 4 + 2]);
            acc[r4 * 4 + 3] = fmaf(xv, wv.w, acc[r4 * 4 + 3]);
        }
    }

    const int i = p / WW, j = p % WW;
    const float lam = 1.f / 96.f;
#pragma unroll
    for (int k = 0; k < 2; ++k)
#pragma unroll
        for (int l = 0; l < 2; ++l) {
            int kl = k * 2 + l;
            float ox = tanhf(acc[kl]);
            float oy = tanhf(acc[4 + kl]);
            float sx = 1.f / (1.f + expf(-acc[8 + kl]));
            float sy = 1.f / (1.f + expf(-acc[12 + kl]));
            int ho = 2 * i + k, wo = 2 * j + l;
            dxdy[((size_t)b * HS + ho) * WSZ + wo] =
                make_float2(lam * ox * sx, lam * oy * sy);
        }
}

// ---------------------------------------------------------------------------
// K2: fused epilogue. Per output pixel:
//   out = upsample(y1)  +  grid_sample(upsample(y2), grid+d)
// Both collapse to small stencils on the low-res planes:
//   base: separable 2x2 (weights from parity pattern)
//   deform: separable (gs-bilinear o upsample-bilinear) -> 3x3 coarse stencil
// Weights computed once per pixel, reused over 64 channels per block.
// ---------------------------------------------------------------------------
__global__ __launch_bounds__(256) void fuse_k2(
    const float* __restrict__ y, const float2* __restrict__ dxdy,
    float* __restrict__ out)
{
    const int t   = threadIdx.x;
    const int wo  = blockIdx.x * 16 + (t & 15);
    const int ho  = blockIdx.y * 16 + (t >> 4);
    const int b   = blockIdx.z >> 2;
    const int oc0 = (blockIdx.z & 3) * 64;

    float2 d = dxdy[((size_t)b * HS + ho) * WSZ + wo];
    // grid_sample source coords on the fine (192) grid
    float ix = ((-1.f + wo * (2.f / 191.f) + d.x + 1.f) * 192.f - 1.f) * 0.5f;
    float iy = ((-1.f + ho * (2.f / 191.f) + d.y + 1.f) * 192.f - 1.f) * 0.5f;
    float fx0 = floorf(ix), fy0 = floorf(iy);
    float wx = ix - fx0, wy = iy - fy0;
    int x0 = (int)fx0, y0i = (int)fy0;

    // --- combined coarse column weights (3 slots from base cbx) ---
    float cw0 = 0.f, cw1 = 0.f, cw2 = 0.f;
    int cbx = 0;
    {
        int xA = x0, xB = x0 + 1;
        bool vA = ((unsigned)xA <= 191u), vB = ((unsigned)xB <= 191u);
        float sA = fmaxf(0.5f * (xA + 0.5f) - 0.5f, 0.f);
        float sB = fmaxf(0.5f * (xB + 0.5f) - 0.5f, 0.f);
        int c0A = (int)sA, c0B = (int)sB;
        float uA = sA - c0A, uB = sB - c0B;
        cbx = vA ? c0A : (vB ? c0B : 0);
        if (vA) {
            float w = 1.f - wx;
            int c1 = min(c0A + 1, 95);
            cw0 += w * (1.f - uA);                       // c0A == cbx
            cw0 += (c1 == cbx) ? w * uA : 0.f;           // clamp case
            cw1 += (c1 == cbx + 1) ? w * uA : 0.f;
        }
        if (vB) {
            float w = wx;
            int c1 = min(c0B + 1, 95);
            int d0 = c0B - cbx, d1 = c1 - cbx;
            float w0 = w * (1.f - uB), w1 = w * uB;
            cw0 += (d0 == 0) ? w0 : 0.f;
            cw1 += (d0 == 1) ? w0 : 0.f;
            cw0 += (d1 == 0) ? w1 : 0.f;
            cw1 += (d1 == 1) ? w1 : 0.f;
            cw2 += (d1 == 2) ? w1 : 0.f;
        }
    }
    // --- combined coarse row weights ---
    float rw0 = 0.f, rw1 = 0.f, rw2 = 0.f;
    int cby = 0;
    {
        int yA = y0i, yB = y0i + 1;
        bool vA = ((unsigned)yA <= 191u), vB = ((unsigned)yB <= 191u);
        float sA = fmaxf(0.5f * (yA + 0.5f) - 0.5f, 0.f);
        float sB = fmaxf(0.5f * (yB + 0.5f) - 0.5f, 0.f);
        int c0A = (int)sA, c0B = (int)sB;
        float uA = sA - c0A, uB = sB - c0B;
        cby = vA ? c0A : (vB ? c0B : 0);
        if (vA) {
            float w = 1.f - wy;
            int c1 = min(c0A + 1, 95);
            rw0 += w * (1.f - uA);
            rw0 += (c1 == cby) ? w * uA : 0.f;
            rw1 += (c1 == cby + 1) ? w * uA : 0.f;
        }
        if (vB) {
            float w = wy;
            int c1 = min(c0B + 1, 95);
            int d0 = c0B - cby, d1 = c1 - cby;
            float w0 = w * (1.f - uB), w1 = w * uB;
            rw0 += (d0 == 0) ? w0 : 0.f;
            rw1 += (d0 == 1) ? w0 : 0.f;
            rw0 += (d1 == 0) ? w1 : 0.f;
            rw1 += (d1 == 1) ? w1 : 0.f;
            rw2 += (d1 == 2) ? w1 : 0.f;
        }
    }

    // 9 combined deform weights + clamped element offsets
    float w00 = rw0 * cw0, w01 = rw0 * cw1, w02 = rw0 * cw2;
    float w10 = rw1 * cw0, w11 = rw1 * cw1, w12 = rw1 * cw2;
    float w20 = rw2 * cw0, w21 = rw2 * cw1, w22 = rw2 * cw2;
    int rr0 = cby * WW;
    int rr1 = min(cby + 1, 95) * WW;
    int rr2 = min(cby + 2, 95) * WW;
    int cc0 = cbx, cc1 = min(cbx + 1, 95), cc2 = min(cbx + 2, 95);
    int o00 = rr0 + cc0, o01 = rr0 + cc1, o02 = rr0 + cc2;
    int o10 = rr1 + cc0, o11 = rr1 + cc1, o12 = rr1 + cc2;
    int o20 = rr2 + cc0, o21 = rr2 + cc1, o22 = rr2 + cc2;

    // base-branch 2x2 upsample taps for (ho, wo)
    float sbr = fmaxf(0.5f * (ho + 0.5f) - 0.5f, 0.f);
    int br0 = (int)sbr; float ur = sbr - br0; int br1 = min(br0 + 1, 95);
    float sbc = fmaxf(0.5f * (wo + 0.5f) - 0.5f, 0.f);
    int bc0 = (int)sbc; float uc = sbc - bc0; int bc1 = min(bc0 + 1, 95);
    float bw00 = (1.f - ur) * (1.f - uc), bw01 = (1.f - ur) * uc;
    float bw10 = ur * (1.f - uc),         bw11 = ur * uc;
    int ob0 = br0 * WW + bc0, ob1 = br0 * WW + bc1;
    int ob2 = br1 * WW + bc0, ob3 = br1 * WW + bc1;

    const float* p1 = y + ((size_t)b * 512 + oc0) * HW;        // y1 (w_base)
    const float* p2 = p1 + (size_t)256 * HW;                   // y2 (w_process)
    float* O = out + (((size_t)b * 256 + oc0) * HS + ho) * WSZ + wo;

#pragma unroll 2
    for (int o = 0; o < 64; ++o) {
        float acc;
        acc = bw00 * p1[ob0];
        acc = fmaf(bw01, p1[ob1], acc);
        acc = fmaf(bw10, p1[ob2], acc);
        acc = fmaf(bw11, p1[ob3], acc);
        acc = fmaf(w00, p2[o00], acc);
        acc = fmaf(w01, p2[o01], acc);
        acc = fmaf(w02, p2[o02], acc);
        acc = fmaf(w10, p2[o10], acc);
        acc = fmaf(w11, p2[o11], acc);
        acc = fmaf(w12, p2[o12], acc);
        acc = fmaf(w20, p2[o20], acc);
        acc = fmaf(w21, p2[o21], acc);
        acc = fmaf(w22, p2[o22], acc);
        O[(size_t)o * HSWS] = acc;
        p1 += HW;
        p2 += HW;
    }
}

// ---------------------------------------------------------------------------
extern "C" void kernel_launch(void* const* d_in, const int* in_sizes, int n_in,
                              void* d_out, int out_size, void* d_ws, size_t ws_size,
                              hipStream_t stream)
{
    const float* x         = (const float*)d_in[0];
    const float* w_process = (const float*)d_in[1];
    const float* w_base    = (const float*)d_in[2];
    const float* w_tc      = (const float*)d_in[3];
    float* out = (float*)d_out;

    // workspace: y (4*512*9216 f32 = 75.5 MB) then dxdy (4*192*192 float2 = 1.2 MB)
    float*  y    = (float*)d_ws;
    float2* dxdy = (float2*)((float*)d_ws + (size_t)4 * 512 * HW);

    hipLaunchKernelGGL(gemm_k1, dim3(72, 4, 4), dim3(256), 0, stream,
                       x, w_base, w_process, y);
    hipLaunchKernelGGL(tconv_k1b, dim3(144), dim3(256), 0, stream,
                       x, w_tc, dxdy);
    hipLaunchKernelGGL(fuse_k2, dim3(12, 12, 16), dim3(256), 0, stream,
                       y, dxdy, out);
}